// Round 1
// baseline (5162.064 us; speedup 1.0000x reference)
//
#include <hip/hip_runtime.h>

// 3-layer LSTM (B=8192, T=336, F=8, H=20) + FC(20->20 relu) + FC(20->1), all fp32.
//
// Parallelization: wave = 3 batch elements x 20 unit-lanes (lanes 60..63 idle).
// Lane (e,j) owns hidden unit j of its element for all 3 layers; c kept in
// registers; h exchanged through LDS *within the wave only* (no barriers:
// per-wave DS ops are in-order, and all reads of h(t-1) precede the write of
// h(t) in program order). Weights live in LDS with padded row strides
// (28 / 44 floats) for bank friendliness; rows read as float4.
// Block = 256 threads (4 waves) = 12 elements; grid = ceil(8192/12) = 683.
// LDS ~42.7 KB -> 3 blocks/CU -> ~12 waves/CU (~3/SIMD).

#define T_LEN 336
#define B_TOT 8192L

__device__ __forceinline__ float sigm(float x) {
  // 1/(1+exp(-x)) = rcp(1 + 2^(-x*log2e))
  return __builtin_amdgcn_rcpf(1.0f + __builtin_amdgcn_exp2f(-1.4426950408889634f * x));
}
__device__ __forceinline__ float tanh_fast(float x) {
  // tanh(x) = 2/(1+exp(-2x)) - 1
  return 2.0f * __builtin_amdgcn_rcpf(1.0f + __builtin_amdgcn_exp2f(-2.8853900817779268f * x)) - 1.0f;
}

__global__ __launch_bounds__(256, 3) void lstm3_fc_kernel(
    const float* __restrict__ x,
    const float* __restrict__ Wih0, const float* __restrict__ Whh0,
    const float* __restrict__ bih0, const float* __restrict__ bhh0,
    const float* __restrict__ Wih1, const float* __restrict__ Whh1,
    const float* __restrict__ bih1, const float* __restrict__ bhh1,
    const float* __restrict__ Wih2, const float* __restrict__ Whh2,
    const float* __restrict__ bih2, const float* __restrict__ bhh2,
    const float* __restrict__ fc1w, const float* __restrict__ fc1b,
    const float* __restrict__ fc2w, const float* __restrict__ fc2b,
    float* __restrict__ out)
{
  // LDS weight layout: row g of layer l = [W_ih row | W_hh row | pad]
  __shared__ float w0[80 * 28];   // 8 + 20       (stride 28: 28 mod 8 == 4, bank-friendly)
  __shared__ float w1[80 * 44];   // 20 + 20 + 4  (stride 44: 44 mod 8 == 4)
  __shared__ float w2[80 * 44];
  __shared__ float cb0[80], cb1[80], cb2[80];   // combined biases b_ih + b_hh
  __shared__ float hs[3][16 * 24];              // h per layer, elem-major, stride 24 (16B aligned)

  const int tid = threadIdx.x;

  // ---- stage weights into LDS ----
  for (int i = tid; i < 80 * 8; i += 256) {
    int g = i >> 3;
    w0[g * 28 + (i & 7)] = Wih0[i];
  }
  for (int i = tid; i < 80 * 20; i += 256) {
    int g = i / 20, k = i - g * 20;
    w0[g * 28 + 8 + k]  = Whh0[i];
    w1[g * 44 + k]      = Wih1[i];
    w1[g * 44 + 20 + k] = Whh1[i];
    w2[g * 44 + k]      = Wih2[i];
    w2[g * 44 + 20 + k] = Whh2[i];
  }
  for (int i = tid; i < 80; i += 256) {
    cb0[i] = bih0[i] + bhh0[i];
    cb1[i] = bih1[i] + bhh1[i];
    cb2[i] = bih2[i] + bhh2[i];
  }
  for (int i = tid; i < 3 * 16 * 24; i += 256) (&hs[0][0])[i] = 0.0f;
  __syncthreads();   // the only barrier in the kernel

  const int lane = tid & 63;
  const int wv   = tid >> 6;
  const int ew   = lane / 20;          // 0..2 live, 3 = idle lanes
  const int j    = lane - ew * 20;     // hidden unit 0..19
  const bool alive = (ew < 3);
  const int eb   = wv * 3 + ew;        // 0..11 live; idle lanes -> 3..12 (safe read slots, never written)
  const long eg  = (long)blockIdx.x * 12 + eb;
  const bool valid = alive && (eg < B_TOT);

  float* h0p = &hs[0][eb * 24];
  float* h1p = &hs[1][eb * 24];
  float* h2p = &hs[2][eb * 24];

  // idle/tail lanes read element 0's x (harmless, avoids divergence on loads)
  const long egs = (valid ? eg : 0);
  const float4* xp = (const float4*)(x + egs * (long)(T_LEN * 8));

  // per-lane gate-row pointers (q = 0:i, 1:f, 2:g, 3:o)
  const float4* R0[4]; const float4* R1[4]; const float4* R2[4];
  float B0[4], B1[4], B2[4];
#pragma unroll
  for (int q = 0; q < 4; ++q) {
    R0[q] = (const float4*)&w0[(q * 20 + j) * 28];
    R1[q] = (const float4*)&w1[(q * 20 + j) * 44];
    R2[q] = (const float4*)&w2[(q * 20 + j) * 44];
    B0[q] = cb0[q * 20 + j];
    B1[q] = cb1[q * 20 + j];
    B2[q] = cb2[q * 20 + j];
  }

  float c0 = 0.f, c1 = 0.f, c2 = 0.f;
  float hA[20], hB[20];
  float acc[4];

#pragma unroll 1
  for (int t = 0; t < T_LEN; ++t) {
    // x(t) for this element: 8 floats, two float4s (aligned: 2688*4 and 32 both %16==0)
    float xv[8];
    {
      float4 a = xp[2 * t], b = xp[2 * t + 1];
      xv[0] = a.x; xv[1] = a.y; xv[2] = a.z; xv[3] = a.w;
      xv[4] = b.x; xv[5] = b.y; xv[6] = b.z; xv[7] = b.w;
    }

    // ---------- layer 0 : gates = Wih0*x + Whh0*h0(t-1) + cb ----------
#pragma unroll
    for (int k = 0; k < 5; ++k) {
      float4 v = ((const float4*)h0p)[k];
      hA[4*k] = v.x; hA[4*k+1] = v.y; hA[4*k+2] = v.z; hA[4*k+3] = v.w;
    }
#pragma unroll
    for (int q = 0; q < 4; ++q) {
      const float4* r = R0[q];
      float s = B0[q];
      float4 v;
      v = r[0]; s += v.x*xv[0] + v.y*xv[1] + v.z*xv[2] + v.w*xv[3];
      v = r[1]; s += v.x*xv[4] + v.y*xv[5] + v.z*xv[6] + v.w*xv[7];
#pragma unroll
      for (int k = 0; k < 5; ++k) {
        v = r[2 + k];
        s += v.x*hA[4*k] + v.y*hA[4*k+1] + v.z*hA[4*k+2] + v.w*hA[4*k+3];
      }
      acc[q] = s;
    }
    {
      float ig = sigm(acc[0]), fg = sigm(acc[1]);
      float gv = tanh_fast(acc[2]), ov = sigm(acc[3]);
      c0 = fg * c0 + ig * gv;
      if (alive) h0p[j] = ov * tanh_fast(c0);   // wave-internal; DS pipe is in-order
    }

    // ---------- layer 1 : gates = Wih1*h0(t) + Whh1*h1(t-1) + cb ----------
#pragma unroll
    for (int k = 0; k < 5; ++k) {
      float4 v = ((const float4*)h0p)[k];
      hA[4*k] = v.x; hA[4*k+1] = v.y; hA[4*k+2] = v.z; hA[4*k+3] = v.w;
      float4 u = ((const float4*)h1p)[k];
      hB[4*k] = u.x; hB[4*k+1] = u.y; hB[4*k+2] = u.z; hB[4*k+3] = u.w;
    }
#pragma unroll
    for (int q = 0; q < 4; ++q) {
      const float4* r = R1[q];
      float s = B1[q];
      float4 v;
#pragma unroll
      for (int k = 0; k < 5; ++k) {
        v = r[k];
        s += v.x*hA[4*k] + v.y*hA[4*k+1] + v.z*hA[4*k+2] + v.w*hA[4*k+3];
      }
#pragma unroll
      for (int k = 0; k < 5; ++k) {
        v = r[5 + k];
        s += v.x*hB[4*k] + v.y*hB[4*k+1] + v.z*hB[4*k+2] + v.w*hB[4*k+3];
      }
      acc[q] = s;
    }
    {
      float ig = sigm(acc[0]), fg = sigm(acc[1]);
      float gv = tanh_fast(acc[2]), ov = sigm(acc[3]);
      c1 = fg * c1 + ig * gv;
      if (alive) h1p[j] = ov * tanh_fast(c1);
    }

    // ---------- layer 2 : gates = Wih2*h1(t) + Whh2*h2(t-1) + cb ----------
#pragma unroll
    for (int k = 0; k < 5; ++k) {
      float4 v = ((const float4*)h1p)[k];
      hA[4*k] = v.x; hA[4*k+1] = v.y; hA[4*k+2] = v.z; hA[4*k+3] = v.w;
      float4 u = ((const float4*)h2p)[k];
      hB[4*k] = u.x; hB[4*k+1] = u.y; hB[4*k+2] = u.z; hB[4*k+3] = u.w;
    }
#pragma unroll
    for (int q = 0; q < 4; ++q) {
      const float4* r = R2[q];
      float s = B2[q];
      float4 v;
#pragma unroll
      for (int k = 0; k < 5; ++k) {
        v = r[k];
        s += v.x*hA[4*k] + v.y*hA[4*k+1] + v.z*hA[4*k+2] + v.w*hA[4*k+3];
      }
#pragma unroll
      for (int k = 0; k < 5; ++k) {
        v = r[5 + k];
        s += v.x*hB[4*k] + v.y*hB[4*k+1] + v.z*hB[4*k+2] + v.w*hB[4*k+3];
      }
      acc[q] = s;
    }
    {
      float ig = sigm(acc[0]), fg = sigm(acc[1]);
      float gv = tanh_fast(acc[2]), ov = sigm(acc[3]);
      c2 = fg * c2 + ig * gv;
      if (alive) h2p[j] = ov * tanh_fast(c2);
    }
  }

  // ---------- FC head: relu(h2 @ fc1w^T + fc1b) @ fc2w^T + fc2b ----------
#pragma unroll
  for (int k = 0; k < 5; ++k) {
    float4 v = ((const float4*)h2p)[k];
    hA[4*k] = v.x; hA[4*k+1] = v.y; hA[4*k+2] = v.z; hA[4*k+3] = v.w;
  }
  {
    float s = fc1b[j];
    const float4* fw = (const float4*)(fc1w + j * 20);   // 80*j bytes, 16B aligned
#pragma unroll
    for (int k = 0; k < 5; ++k) {
      float4 v = fw[k];
      s += v.x*hA[4*k] + v.y*hA[4*k+1] + v.z*hA[4*k+2] + v.w*hA[4*k+3];
    }
    s = fmaxf(s, 0.0f);
    if (alive) h0p[j] = s;       // stage fc1 output in hs[0] (wave-internal)
  }
  if (valid && j == 0) {
    float r = fc2b[0];
#pragma unroll
    for (int k = 0; k < 5; ++k) {
      float4 wv2 = ((const float4*)fc2w)[k];
      float4 hv  = ((const float4*)h0p)[k];
      r += wv2.x*hv.x + wv2.y*hv.y + wv2.z*hv.z + wv2.w*hv.w;
    }
    out[eg] = r;
  }
}

extern "C" void kernel_launch(void* const* d_in, const int* in_sizes, int n_in,
                              void* d_out, int out_size, void* d_ws, size_t ws_size,
                              hipStream_t stream) {
  const float* x    = (const float*)d_in[0];
  const float* Wih0 = (const float*)d_in[1];
  const float* Whh0 = (const float*)d_in[2];
  const float* bih0 = (const float*)d_in[3];
  const float* bhh0 = (const float*)d_in[4];
  const float* Wih1 = (const float*)d_in[5];
  const float* Whh1 = (const float*)d_in[6];
  const float* bih1 = (const float*)d_in[7];
  const float* bhh1 = (const float*)d_in[8];
  const float* Wih2 = (const float*)d_in[9];
  const float* Whh2 = (const float*)d_in[10];
  const float* bih2 = (const float*)d_in[11];
  const float* bhh2 = (const float*)d_in[12];
  const float* fc1w = (const float*)d_in[13];
  const float* fc1b = (const float*)d_in[14];
  const float* fc2w = (const float*)d_in[15];
  const float* fc2b = (const float*)d_in[16];
  float* out = (float*)d_out;

  const int nblk = (8192 + 11) / 12;   // 683
  hipLaunchKernelGGL(lstm3_fc_kernel, dim3(nblk), dim3(256), 0, stream,
                     x, Wih0, Whh0, bih0, bhh0,
                     Wih1, Whh1, bih1, bhh1,
                     Wih2, Whh2, bih2, bhh2,
                     fc1w, fc1b, fc2w, fc2b, out);
}